// Round 3
// baseline (128.952 us; speedup 1.0000x reference)
//
#include <hip/hip_runtime.h>
#include <hip/hip_bf16.h>
#include <math.h>

// Problem: P=20000, d=128, C=512, h=4 (fixed dataset). d==128, h==4 assumed.
#define D_DIM 128
#define H_DIM 4

typedef __attribute__((ext_vector_type(4))) float f32x4;
typedef __attribute__((ext_vector_type(8))) __bf16 bf16x8v;

__device__ inline unsigned short f2bf(float f) {
    __hip_bfloat16 b = __float2bfloat16(f);
    return *reinterpret_cast<unsigned short*>(&b);
}

// ---- build normalized K rows in bf16 (row-major [Ppad][128]) + 1/norm ----
__global__ __launch_bounds__(256) void k_knb(
    const float* __restrict__ K, unsigned int* __restrict__ Knb,
    float* __restrict__ rnK, int P, int Ppad)
{
    int row = blockIdx.x * 4 + (threadIdx.x >> 6);
    int lane = threadIdx.x & 63;
    if (row >= Ppad) return;
    if (row >= P) { Knb[(size_t)row * 64 + lane] = 0u; return; }
    float2 v = ((const float2*)(K + (size_t)row * D_DIM))[lane];
    float ss = v.x * v.x + v.y * v.y;
    #pragma unroll
    for (int off = 1; off < 64; off <<= 1) ss += __shfl_xor(ss, off);
    float rn = 1.0f / fmaxf(sqrtf(ss), 1e-12f);
    unsigned int pk = (unsigned)f2bf(v.x * rn) | ((unsigned)f2bf(v.y * rn) << 16);
    Knb[(size_t)row * 64 + lane] = pk;
    if (lane == 0) rnK[row] = rn;
}

// ---- build normalized Theta rows: bf16 [NJ][128] and fp32 [NJ][128] ----
__global__ __launch_bounds__(256) void k_tn(
    const float* __restrict__ Theta, unsigned int* __restrict__ Tnb,
    float* __restrict__ Tn32, int NJ)
{
    int j = blockIdx.x * 4 + (threadIdx.x >> 6);
    int lane = threadIdx.x & 63;
    if (j >= NJ) return;
    int c = j >> 2, s = j & 3;
    const float* base = Theta + (size_t)c * (D_DIM * H_DIM) + s;
    float t0 = base[(2 * lane) * H_DIM];
    float t1 = base[(2 * lane + 1) * H_DIM];
    float ss = t0 * t0 + t1 * t1;
    #pragma unroll
    for (int off = 1; off < 64; off <<= 1) ss += __shfl_xor(ss, off);
    float rn = 1.0f / fmaxf(sqrtf(ss), 1e-12f);
    float n0 = t0 * rn, n1 = t1 * rn;
    Tnb[(size_t)j * 64 + lane] = (unsigned)f2bf(n0) | ((unsigned)f2bf(n1) << 16);
    float2 w; w.x = n0; w.y = n1;
    ((float2*)(Tn32 + (size_t)j * D_DIM))[lane] = w;
}

// ---- head_of scatter: head_of[head_idx[c]] = min c ----
__global__ void k_scatter(const int* __restrict__ head_idx, int* __restrict__ head_of, int C) {
    int c = blockIdx.x * blockDim.x + threadIdx.x;
    if (c < C) atomicMin(&head_of[head_idx[c]], c);
}

// ---- bf16 MFMA GEMM, fused per-(j, 32p-chunk) max.  D[j][p]=Tn·Kn^T ----
// block: 256 thr = 4 waves (2x2), tile 128j x 128p, K=128 in one LDS stage.
__global__ __launch_bounds__(256) void k_mfma_max(
    const unsigned short* __restrict__ Knb, const unsigned short* __restrict__ Tnb,
    float* __restrict__ pv2, int NT4)
{
    __shared__ __align__(16) unsigned short As[128 * 128];  // Tn tile  32 KB
    __shared__ __align__(16) unsigned short Bs[128 * 128];  // Kn tile  32 KB

    int tid = threadIdx.x;
    int p0 = blockIdx.x * 128, j0 = blockIdx.y * 128;
    int lane = tid & 63;
    int wave = tid >> 6;

    // stage via global_load_lds: linear LDS dest, inverse-XOR-swizzled global src.
    // LDS chunk (r, c) holds global chunk (c ^ (r&7)); read side XORs again.
    {
        int rr = lane >> 4, cc = lane & 15;
        const unsigned short* gA = Tnb + (size_t)j0 * 128;
        const unsigned short* gB = Knb + (size_t)p0 * 128;
        #pragma unroll
        for (int i = 0; i < 8; i++) {
            int r0 = wave * 32 + i * 4;
            int r = r0 + rr;
            int sc = (cc ^ (r & 7)) << 3;
            __builtin_amdgcn_global_load_lds(
                (const __attribute__((address_space(1))) unsigned int*)(gA + (size_t)r * 128 + sc),
                (__attribute__((address_space(3))) unsigned int*)&As[r0 * 128], 16, 0, 0);
            __builtin_amdgcn_global_load_lds(
                (const __attribute__((address_space(1))) unsigned int*)(gB + (size_t)r * 128 + sc),
                (__attribute__((address_space(3))) unsigned int*)&Bs[r0 * 128], 16, 0, 0);
        }
    }
    __syncthreads();

    int wm = wave >> 1, wn = wave & 1;
    int lr = lane & 15, lg = lane >> 4;

    f32x4 acc[4][4];
    #pragma unroll
    for (int m = 0; m < 4; m++)
        #pragma unroll
        for (int n = 0; n < 4; n++) { f32x4 z = {0.f, 0.f, 0.f, 0.f}; acc[m][n] = z; }

    #pragma unroll
    for (int ks = 0; ks < 4; ks++) {
        int koff = (8 * lg + 32 * ks) ^ ((lr & 7) << 3);
        bf16x8v af[4], bv[4];
        #pragma unroll
        for (int m = 0; m < 4; m++) {
            int row = 64 * wm + 16 * m + lr;
            af[m] = *(const bf16x8v*)&As[row * 128 + koff];
        }
        #pragma unroll
        for (int n = 0; n < 4; n++) {
            int row = 64 * wn + 16 * n + lr;
            bv[n] = *(const bf16x8v*)&Bs[row * 128 + koff];
        }
        #pragma unroll
        for (int m = 0; m < 4; m++)
            #pragma unroll
            for (int n = 0; n < 4; n++)
                acc[m][n] = __builtin_amdgcn_mfma_f32_16x16x32_bf16(af[m], bv[n], acc[m][n], 0, 0, 0);
    }

    // epilogue: per-32p-chunk max.  C/D: col(p)=lane&15, row(j)=4*(lane>>4)+reg
    __syncthreads();
    float* red = (float*)As;   // [128 j][4 chunk]
    #pragma unroll
    for (int m = 0; m < 4; m++) {
        #pragma unroll
        for (int n2 = 0; n2 < 2; n2++) {
            f32x4 a0 = acc[m][2 * n2], a1 = acc[m][2 * n2 + 1];
            float t0 = fmaxf(a0[0], a1[0]);
            float t1 = fmaxf(a0[1], a1[1]);
            float t2 = fmaxf(a0[2], a1[2]);
            float t3 = fmaxf(a0[3], a1[3]);
            #pragma unroll
            for (int off = 1; off <= 8; off <<= 1) {
                t0 = fmaxf(t0, __shfl_xor(t0, off));
                t1 = fmaxf(t1, __shfl_xor(t1, off));
                t2 = fmaxf(t2, __shfl_xor(t2, off));
                t3 = fmaxf(t3, __shfl_xor(t3, off));
            }
            if (lr == 0) {
                int jb = 64 * wm + 16 * m + 4 * lg;
                int ch = 2 * wn + n2;
                red[(jb + 0) * 4 + ch] = t0;
                red[(jb + 1) * 4 + ch] = t1;
                red[(jb + 2) * 4 + ch] = t2;
                red[(jb + 3) * 4 + ch] = t3;
            }
        }
    }
    __syncthreads();
    #pragma unroll
    for (int e = tid; e < 512; e += 256) {
        int jl = e >> 2, ch = e & 3;
        pv2[(size_t)(j0 + jl) * NT4 + blockIdx.x * 4 + ch] = red[jl * 4 + ch];
    }
}

// ---- per-j threshold: max over chunk maxes − 2*eps ----
__global__ __launch_bounds__(256) void k_thr(const float* __restrict__ pv2,
                                             float* __restrict__ thr, int NT4) {
    int wave = threadIdx.x >> 6, lane = threadIdx.x & 63;
    int j = blockIdx.x * 4 + wave;
    const float* row = pv2 + (size_t)j * NT4;
    float m = -INFINITY;
    for (int t = lane; t < NT4; t += 64) m = fmaxf(m, row[t]);
    #pragma unroll
    for (int off = 32; off; off >>= 1) m = fmaxf(m, __shfl_xor(m, off));
    if (lane == 0) thr[j] = m - 0.009f;   // 2*eps bf16 unit-vector dot bound
}

// ---- emit candidate (j, chunk) pairs ----
__global__ __launch_bounds__(256) void k_emit(const float* __restrict__ pv2,
                                              const float* __restrict__ thr,
                                              unsigned int* __restrict__ wl,
                                              int* __restrict__ wl_count, int NT4) {
    int j = blockIdx.y;
    int t = blockIdx.x * 256 + threadIdx.x;
    if (t >= NT4) return;
    float v = pv2[(size_t)j * NT4 + t];
    if (v >= thr[j]) {
        int pos = atomicAdd(wl_count, 1);
        wl[pos] = ((unsigned)j << 11) | (unsigned)t;
    }
}

// ---- exact fp32 rescore: one wave per candidate 32p-chunk ----
__global__ __launch_bounds__(256) void k_rescore2(
    const unsigned int* __restrict__ wl, const int* __restrict__ wl_count,
    const float* __restrict__ K, const float* __restrict__ rnK,
    const float* __restrict__ Tn32, unsigned long long* __restrict__ cand, int P)
{
    int lane = threadIdx.x & 63;
    int wid = blockIdx.x * 4 + (threadIdx.x >> 6);
    int nw = gridDim.x * 4;
    int n = *wl_count;
    int half = lane & 1;        // which 64-elem half of the row
    int pl = lane >> 1;         // p within chunk (0..31)
    for (int i = wid; i < n; i += nw) {
        unsigned int e = wl[i];
        int j = (int)(e >> 11), t = (int)(e & 2047u);
        int p = t * 32 + pl;
        bool ok = (p < P);
        int pc = ok ? p : 0;
        const float4* kp = (const float4*)(K + (size_t)pc * D_DIM + half * 64);
        const float4* tp = (const float4*)(Tn32 + (size_t)j * D_DIM + half * 64);
        float sx = 0.f, sy = 0.f, sz = 0.f, sw = 0.f;
        #pragma unroll
        for (int k4 = 0; k4 < 16; k4++) {
            float4 a = kp[k4], b = tp[k4];
            sx = fmaf(a.x, b.x, sx); sy = fmaf(a.y, b.y, sy);
            sz = fmaf(a.z, b.z, sz); sw = fmaf(a.w, b.w, sw);
        }
        float dot = (sx + sy) + (sz + sw);
        dot += __shfl_xor(dot, 1);           // combine halves
        float v = ok ? dot * rnK[pc] : -INFINITY;
        int bp = p;
        #pragma unroll
        for (int off = 2; off < 64; off <<= 1) {
            float ov = __shfl_xor(v, off);
            int op = __shfl_xor(bp, off);
            if (ov > v || (ov == v && op < bp)) { v = ov; bp = op; }
        }
        if (lane == 0) {
            unsigned int ub = __float_as_uint(v);
            ub = (ub & 0x80000000u) ? ~ub : (ub | 0x80000000u);
            unsigned long long key =
                ((unsigned long long)ub << 32) | (unsigned int)(0x7FFFFFFF - bp);
            atomicMax(&cand[j], key);
        }
    }
}

// ---- copy initial_val -> out ----
__global__ void k_copy(const float* __restrict__ a, float* __restrict__ o, int n) {
    int i = blockIdx.x * blockDim.x + threadIdx.x;
    if (i < n) o[i] = a[i];
}

// ---- 6-iteration soft-logic loop, single block ----
__global__ __launch_bounds__(1024) void k_logic(
    const int* __restrict__ head_idx, const float* __restrict__ initial_val,
    const unsigned long long* __restrict__ cand, const int* __restrict__ head_of,
    float* __restrict__ out, int C)
{
    __shared__ float hval[1024];
    __shared__ float elds[1024];
    int c = threadIdx.x;   // blockDim.x == C
    int h = head_idx[c];
    int myslot = head_of[h];           // min clause index sharing this head
    hval[c] = initial_val[h];

    float cf[H_DIM], v0[H_DIM]; int bs[H_DIM];
    #pragma unroll
    for (int s = 0; s < H_DIM; s++) {
        unsigned long long key = cand[c * H_DIM + s];
        unsigned int ub = (unsigned int)(key >> 32);
        unsigned int fb = (ub & 0x80000000u) ? (ub ^ 0x80000000u) : ~ub;
        cf[s] = __uint_as_float(fb);
        int b = 0x7FFFFFFF - (int)(key & 0xFFFFFFFFu);
        v0[s] = initial_val[b];
        int ho = head_of[b];
        bs[s] = (ho < C) ? ho : -1;
    }
    __syncthreads();

    const float inv_tau = 20.0f;            // 1/TAU
    const float logn = logf(2.0f * H_DIM);  // log 8
    const float beta = 8.0f;

    for (int it = 0; it < 6; it++) {
        float x[2 * H_DIM];
        #pragma unroll
        for (int s = 0; s < H_DIM; s++) {
            x[s] = cf[s];
            x[H_DIM + s] = (bs[s] >= 0) ? hval[bs[s]] : v0[s];
        }
        float cur = hval[myslot];
        elds[c] = 0.f;
        __syncthreads();

        float m = x[0];
        #pragma unroll
        for (int i = 1; i < 2 * H_DIM; i++) m = fminf(m, x[i]);
        float ssum = 0.f;
        #pragma unroll
        for (int i = 0; i < 2 * H_DIM; i++) ssum += expf((m - x[i]) * inv_tau);
        float g = -inv_tau * ((-m * inv_tau + logf(ssum)) - logn);
        g = fminf(fmaxf(g, 0.f), 1.f);
        float w = expf(beta * g);
        atomicAdd(&elds[myslot], w);
        __syncthreads();

        float e = elds[myslot];
        float gh = logf(fmaxf(e, 1e-38f)) / beta;
        float nv = fmaxf(cur, gh);
        if (myslot == c) hval[c] = nv;
        __syncthreads();
    }

    if (myslot == c) out[h] = hval[c];
}

// ---------------- launch ----------------
extern "C" void kernel_launch(void* const* d_in, const int* in_sizes, int n_in,
                              void* d_out, int out_size, void* d_ws, size_t ws_size,
                              hipStream_t stream) {
    const float* K        = (const float*)d_in[0];
    const float* Theta    = (const float*)d_in[1];
    const int*   head_idx = (const int*)d_in[2];
    const float* initial  = (const float*)d_in[3];
    float* out = (float*)d_out;

    int P  = in_sizes[3];
    int C  = in_sizes[2];
    int NJ = C * H_DIM;                     // 2048
    int Ppad = ((P + 127) / 128) * 128;     // 20096
    int NT = Ppad / 128;                    // 157
    int NT4 = NT * 4;                       // 628 (32-p chunks)

    char* w = (char*)d_ws;
    size_t off = 0;
    auto alloc = [&](size_t bytes) { void* p = w + off; off += (bytes + 255) & ~(size_t)255; return p; };
    unsigned int* Knb  = (unsigned int*)alloc((size_t)Ppad * D_DIM * 2);
    unsigned int* Tnb  = (unsigned int*)alloc((size_t)NJ * D_DIM * 2);
    float* Tn32 = (float*)alloc((size_t)NJ * D_DIM * 4);
    float* rnK  = (float*)alloc((size_t)P * 4);
    float* pv2  = (float*)alloc((size_t)NJ * NT4 * 4);
    float* thr  = (float*)alloc((size_t)NJ * 4);
    unsigned int* wl = (unsigned int*)alloc((size_t)NJ * NT4 * 4);
    int* wl_count = (int*)alloc(256);
    unsigned long long* cand = (unsigned long long*)alloc((size_t)NJ * 8);
    int* head_of = (int*)alloc((size_t)P * 4);
    (void)ws_size;

    hipMemsetAsync(head_of, 0x7F, (size_t)P * 4, stream);
    hipMemsetAsync(wl_count, 0, 4, stream);
    hipMemsetAsync(cand, 0, (size_t)NJ * 8, stream);

    k_scatter<<<(C + 255) / 256, 256, 0, stream>>>(head_idx, head_of, C);
    k_knb<<<(Ppad + 3) / 4, 256, 0, stream>>>(K, Knb, rnK, P, Ppad);
    k_tn<<<(NJ + 3) / 4, 256, 0, stream>>>(Theta, Tnb, Tn32, NJ);

    dim3 grid(NT, NJ / 128);
    k_mfma_max<<<grid, 256, 0, stream>>>((const unsigned short*)Knb,
                                         (const unsigned short*)Tnb, pv2, NT4);

    k_thr<<<NJ / 4, 256, 0, stream>>>(pv2, thr, NT4);
    dim3 egrid((NT4 + 255) / 256, NJ);
    k_emit<<<egrid, 256, 0, stream>>>(pv2, thr, wl, wl_count, NT4);
    k_rescore2<<<1024, 256, 0, stream>>>(wl, wl_count, K, rnK, Tn32, cand, P);

    k_copy<<<(P + 255) / 256, 256, 0, stream>>>(initial, out, P);
    k_logic<<<1, C, 0, stream>>>(head_idx, initial, cand, head_of, out, C);
}

// Round 4
// 120.054 us; speedup vs baseline: 1.0741x; 1.0741x over previous
//
#include <hip/hip_runtime.h>
#include <hip/hip_bf16.h>
#include <math.h>

// Problem: P=20000, d=128, C=512, h=4 (fixed dataset). d==128, h==4 assumed.
#define D_DIM 128
#define H_DIM 4

typedef __attribute__((ext_vector_type(4))) float f32x4;
typedef __attribute__((ext_vector_type(8))) __bf16 bf16x8v;

__device__ inline unsigned short f2bf(float f) {
    __hip_bfloat16 b = __float2bfloat16(f);
    return *reinterpret_cast<unsigned short*>(&b);
}

// ---- build normalized K rows in bf16 [Ppad][128] + 1/norm + init head_of/out ----
__global__ __launch_bounds__(256) void k_knb(
    const float* __restrict__ K, unsigned int* __restrict__ Knb,
    float* __restrict__ rnK, const float* __restrict__ initial,
    float* __restrict__ out, int* __restrict__ head_of, int P, int Ppad)
{
    int row = blockIdx.x * 4 + (threadIdx.x >> 6);
    int lane = threadIdx.x & 63;
    if (row >= Ppad) return;
    if (row >= P) { Knb[(size_t)row * 64 + lane] = 0u; return; }
    float2 v = ((const float2*)(K + (size_t)row * D_DIM))[lane];
    float ss = v.x * v.x + v.y * v.y;
    #pragma unroll
    for (int off = 1; off < 64; off <<= 1) ss += __shfl_xor(ss, off);
    float rn = 1.0f / fmaxf(sqrtf(ss), 1e-12f);
    unsigned int pk = (unsigned)f2bf(v.x * rn) | ((unsigned)f2bf(v.y * rn) << 16);
    Knb[(size_t)row * 64 + lane] = pk;
    if (lane == 0) {
        rnK[row] = rn;
        out[row] = initial[row];
        head_of[row] = 0x7FFFFFFF;
    }
}

// ---- normalized Theta rows: bf16 [NJ][128] and fp32 [NJ][128]; zero wl_count ----
__global__ __launch_bounds__(256) void k_tn(
    const float* __restrict__ Theta, unsigned int* __restrict__ Tnb,
    float* __restrict__ Tn32, int* __restrict__ wl_count, int NJ)
{
    if (blockIdx.x == 0 && threadIdx.x == 0) *wl_count = 0;
    int j = blockIdx.x * 4 + (threadIdx.x >> 6);
    int lane = threadIdx.x & 63;
    if (j >= NJ) return;
    int c = j >> 2, s = j & 3;
    const float* base = Theta + (size_t)c * (D_DIM * H_DIM) + s;
    float t0 = base[(2 * lane) * H_DIM];
    float t1 = base[(2 * lane + 1) * H_DIM];
    float ss = t0 * t0 + t1 * t1;
    #pragma unroll
    for (int off = 1; off < 64; off <<= 1) ss += __shfl_xor(ss, off);
    float rn = 1.0f / fmaxf(sqrtf(ss), 1e-12f);
    float n0 = t0 * rn, n1 = t1 * rn;
    Tnb[(size_t)j * 64 + lane] = (unsigned)f2bf(n0) | ((unsigned)f2bf(n1) << 16);
    float2 w; w.x = n0; w.y = n1;
    ((float2*)(Tn32 + (size_t)j * D_DIM))[lane] = w;
}

// ---- head_of scatter: head_of[head_idx[c]] = min c  (after k_knb init) ----
__global__ void k_scatter(const int* __restrict__ head_idx, int* __restrict__ head_of, int C) {
    int c = blockIdx.x * blockDim.x + threadIdx.x;
    if (c < C) atomicMin(&head_of[head_idx[c]], c);
}

// ---- bf16 MFMA GEMM, fused per-(j, 32p-chunk) max.  D[j][p]=Tn·Kn^T ----
__global__ __launch_bounds__(256) void k_mfma_max(
    const unsigned short* __restrict__ Knb, const unsigned short* __restrict__ Tnb,
    float* __restrict__ pv2, int NT4)
{
    __shared__ __align__(16) unsigned short As[128 * 128];  // Tn tile  32 KB
    __shared__ __align__(16) unsigned short Bs[128 * 128];  // Kn tile  32 KB

    int tid = threadIdx.x;
    int p0 = blockIdx.x * 128, j0 = blockIdx.y * 128;
    int lane = tid & 63;
    int wave = tid >> 6;

    // stage via global_load_lds: linear LDS dest, inverse-XOR-swizzled global src.
    {
        int rr = lane >> 4, cc = lane & 15;
        const unsigned short* gA = Tnb + (size_t)j0 * 128;
        const unsigned short* gB = Knb + (size_t)p0 * 128;
        #pragma unroll
        for (int i = 0; i < 8; i++) {
            int r0 = wave * 32 + i * 4;
            int r = r0 + rr;
            int sc = (cc ^ (r & 7)) << 3;
            __builtin_amdgcn_global_load_lds(
                (const __attribute__((address_space(1))) unsigned int*)(gA + (size_t)r * 128 + sc),
                (__attribute__((address_space(3))) unsigned int*)&As[r0 * 128], 16, 0, 0);
            __builtin_amdgcn_global_load_lds(
                (const __attribute__((address_space(1))) unsigned int*)(gB + (size_t)r * 128 + sc),
                (__attribute__((address_space(3))) unsigned int*)&Bs[r0 * 128], 16, 0, 0);
        }
    }
    __syncthreads();

    int wm = wave >> 1, wn = wave & 1;
    int lr = lane & 15, lg = lane >> 4;

    f32x4 acc[4][4];
    #pragma unroll
    for (int m = 0; m < 4; m++)
        #pragma unroll
        for (int n = 0; n < 4; n++) { f32x4 z = {0.f, 0.f, 0.f, 0.f}; acc[m][n] = z; }

    #pragma unroll
    for (int ks = 0; ks < 4; ks++) {
        int koff = (8 * lg + 32 * ks) ^ ((lr & 7) << 3);
        bf16x8v af[4], bv[4];
        #pragma unroll
        for (int m = 0; m < 4; m++) {
            int row = 64 * wm + 16 * m + lr;
            af[m] = *(const bf16x8v*)&As[row * 128 + koff];
        }
        #pragma unroll
        for (int n = 0; n < 4; n++) {
            int row = 64 * wn + 16 * n + lr;
            bv[n] = *(const bf16x8v*)&Bs[row * 128 + koff];
        }
        #pragma unroll
        for (int m = 0; m < 4; m++)
            #pragma unroll
            for (int n = 0; n < 4; n++)
                acc[m][n] = __builtin_amdgcn_mfma_f32_16x16x32_bf16(af[m], bv[n], acc[m][n], 0, 0, 0);
    }

    // epilogue: per-32p-chunk max.  C/D: col(p)=lane&15, row(j)=4*(lane>>4)+reg
    __syncthreads();
    float* red = (float*)As;   // [128 j][4 chunk]
    #pragma unroll
    for (int m = 0; m < 4; m++) {
        #pragma unroll
        for (int n2 = 0; n2 < 2; n2++) {
            f32x4 a0 = acc[m][2 * n2], a1 = acc[m][2 * n2 + 1];
            float t0 = fmaxf(a0[0], a1[0]);
            float t1 = fmaxf(a0[1], a1[1]);
            float t2 = fmaxf(a0[2], a1[2]);
            float t3 = fmaxf(a0[3], a1[3]);
            #pragma unroll
            for (int off = 1; off <= 8; off <<= 1) {
                t0 = fmaxf(t0, __shfl_xor(t0, off));
                t1 = fmaxf(t1, __shfl_xor(t1, off));
                t2 = fmaxf(t2, __shfl_xor(t2, off));
                t3 = fmaxf(t3, __shfl_xor(t3, off));
            }
            if (lr == 0) {
                int jb = 64 * wm + 16 * m + 4 * lg;
                int ch = 2 * wn + n2;
                red[(jb + 0) * 4 + ch] = t0;
                red[(jb + 1) * 4 + ch] = t1;
                red[(jb + 2) * 4 + ch] = t2;
                red[(jb + 3) * 4 + ch] = t3;
            }
        }
    }
    __syncthreads();
    #pragma unroll
    for (int e = tid; e < 512; e += 256) {
        int jl = e >> 2, ch = e & 3;
        pv2[(size_t)(j0 + jl) * NT4 + blockIdx.x * 4 + ch] = red[jl * 4 + ch];
    }
}

// ---- fused: per-j threshold + candidate emit + cand zero (wave per j) ----
__global__ __launch_bounds__(256) void k_emitf(
    const float* __restrict__ pv2, unsigned int* __restrict__ wl,
    int* __restrict__ wl_count, unsigned long long* __restrict__ cand, int NT4)
{
    int wave = threadIdx.x >> 6, lane = threadIdx.x & 63;
    int j = blockIdx.x * 4 + wave;
    const float* row = pv2 + (size_t)j * NT4;
    float m = -INFINITY;
    for (int t = lane; t < NT4; t += 64) m = fmaxf(m, row[t]);
    #pragma unroll
    for (int off = 32; off; off >>= 1) m = fmaxf(m, __shfl_xor(m, off));
    float thr = m - 0.009f;   // 2*eps bf16 unit-vector dot bound
    if (lane == 0) cand[j] = 0ULL;   // rescore2 runs strictly after this kernel
    for (int t = lane; t < NT4; t += 64) {
        if (row[t] >= thr) {
            int pos = atomicAdd(wl_count, 1);
            wl[pos] = ((unsigned)j << 11) | (unsigned)t;
        }
    }
}

// ---- exact fp32 rescore: one wave per candidate 32p-chunk ----
__global__ __launch_bounds__(256) void k_rescore2(
    const unsigned int* __restrict__ wl, const int* __restrict__ wl_count,
    const float* __restrict__ K, const float* __restrict__ rnK,
    const float* __restrict__ Tn32, unsigned long long* __restrict__ cand, int P)
{
    int lane = threadIdx.x & 63;
    int wid = blockIdx.x * 4 + (threadIdx.x >> 6);
    int nw = gridDim.x * 4;
    int n = *wl_count;
    int half = lane & 1;        // which 64-elem half of the row
    int pl = lane >> 1;         // p within chunk (0..31)
    for (int i = wid; i < n; i += nw) {
        unsigned int e = wl[i];
        int j = (int)(e >> 11), t = (int)(e & 2047u);
        int p = t * 32 + pl;
        bool ok = (p < P);
        int pc = ok ? p : 0;
        const float4* kp = (const float4*)(K + (size_t)pc * D_DIM + half * 64);
        const float4* tp = (const float4*)(Tn32 + (size_t)j * D_DIM + half * 64);
        float sx = 0.f, sy = 0.f, sz = 0.f, sw = 0.f;
        #pragma unroll
        for (int k4 = 0; k4 < 16; k4++) {
            float4 a = kp[k4], b = tp[k4];
            sx = fmaf(a.x, b.x, sx); sy = fmaf(a.y, b.y, sy);
            sz = fmaf(a.z, b.z, sz); sw = fmaf(a.w, b.w, sw);
        }
        float dot = (sx + sy) + (sz + sw);
        dot += __shfl_xor(dot, 1);           // combine halves
        float v = ok ? dot * rnK[pc] : -INFINITY;
        int bp = p;
        #pragma unroll
        for (int off = 2; off < 64; off <<= 1) {
            float ov = __shfl_xor(v, off);
            int op = __shfl_xor(bp, off);
            if (ov > v || (ov == v && op < bp)) { v = ov; bp = op; }
        }
        if (lane == 0) {
            unsigned int ub = __float_as_uint(v);
            ub = (ub & 0x80000000u) ? ~ub : (ub | 0x80000000u);
            unsigned long long key =
                ((unsigned long long)ub << 32) | (unsigned int)(0x7FFFFFFF - bp);
            atomicMax(&cand[j], key);
        }
    }
}

// ---- 6-iteration soft-logic loop, single block ----
__global__ __launch_bounds__(1024) void k_logic(
    const int* __restrict__ head_idx, const float* __restrict__ initial_val,
    const unsigned long long* __restrict__ cand, const int* __restrict__ head_of,
    float* __restrict__ out, int C)
{
    __shared__ float hval[1024];
    __shared__ float elds[1024];
    int c = threadIdx.x;   // blockDim.x == C
    int h = head_idx[c];
    int myslot = head_of[h];           // min clause index sharing this head
    hval[c] = initial_val[h];

    float cf[H_DIM], v0[H_DIM]; int bs[H_DIM];
    #pragma unroll
    for (int s = 0; s < H_DIM; s++) {
        unsigned long long key = cand[c * H_DIM + s];
        unsigned int ub = (unsigned int)(key >> 32);
        unsigned int fb = (ub & 0x80000000u) ? (ub ^ 0x80000000u) : ~ub;
        cf[s] = __uint_as_float(fb);
        int b = 0x7FFFFFFF - (int)(key & 0xFFFFFFFFu);
        v0[s] = initial_val[b];
        int ho = head_of[b];
        bs[s] = (ho < C) ? ho : -1;
    }
    __syncthreads();

    const float inv_tau = 20.0f;            // 1/TAU
    const float logn = logf(2.0f * H_DIM);  // log 8
    const float beta = 8.0f;

    for (int it = 0; it < 6; it++) {
        float x[2 * H_DIM];
        #pragma unroll
        for (int s = 0; s < H_DIM; s++) {
            x[s] = cf[s];
            x[H_DIM + s] = (bs[s] >= 0) ? hval[bs[s]] : v0[s];
        }
        float cur = hval[myslot];
        elds[c] = 0.f;
        __syncthreads();

        float m = x[0];
        #pragma unroll
        for (int i = 1; i < 2 * H_DIM; i++) m = fminf(m, x[i]);
        float ssum = 0.f;
        #pragma unroll
        for (int i = 0; i < 2 * H_DIM; i++) ssum += expf((m - x[i]) * inv_tau);
        float g = -inv_tau * ((-m * inv_tau + logf(ssum)) - logn);
        g = fminf(fmaxf(g, 0.f), 1.f);
        float w = expf(beta * g);
        atomicAdd(&elds[myslot], w);
        __syncthreads();

        float e = elds[myslot];
        float gh = logf(fmaxf(e, 1e-38f)) / beta;
        float nv = fmaxf(cur, gh);
        if (myslot == c) hval[c] = nv;
        __syncthreads();
    }

    if (myslot == c) out[h] = hval[c];
}

// ---------------- launch ----------------
extern "C" void kernel_launch(void* const* d_in, const int* in_sizes, int n_in,
                              void* d_out, int out_size, void* d_ws, size_t ws_size,
                              hipStream_t stream) {
    const float* K        = (const float*)d_in[0];
    const float* Theta    = (const float*)d_in[1];
    const int*   head_idx = (const int*)d_in[2];
    const float* initial  = (const float*)d_in[3];
    float* out = (float*)d_out;

    int P  = in_sizes[3];
    int C  = in_sizes[2];
    int NJ = C * H_DIM;                     // 2048
    int Ppad = ((P + 127) / 128) * 128;     // 20096
    int NT = Ppad / 128;                    // 157
    int NT4 = NT * 4;                       // 628 (32-p chunks)

    char* w = (char*)d_ws;
    size_t off = 0;
    auto alloc = [&](size_t bytes) { void* p = w + off; off += (bytes + 255) & ~(size_t)255; return p; };
    unsigned int* Knb  = (unsigned int*)alloc((size_t)Ppad * D_DIM * 2);
    unsigned int* Tnb  = (unsigned int*)alloc((size_t)NJ * D_DIM * 2);
    float* Tn32 = (float*)alloc((size_t)NJ * D_DIM * 4);
    float* rnK  = (float*)alloc((size_t)P * 4);
    float* pv2  = (float*)alloc((size_t)NJ * NT4 * 4);
    unsigned int* wl = (unsigned int*)alloc((size_t)NJ * NT4 * 4);
    int* wl_count = (int*)alloc(256);
    unsigned long long* cand = (unsigned long long*)alloc((size_t)NJ * 8);
    int* head_of = (int*)alloc((size_t)P * 4);
    (void)ws_size;

    k_knb<<<(Ppad + 3) / 4, 256, 0, stream>>>(K, Knb, rnK, initial, out, head_of, P, Ppad);
    k_tn<<<(NJ + 3) / 4, 256, 0, stream>>>(Theta, Tnb, Tn32, wl_count, NJ);
    k_scatter<<<(C + 255) / 256, 256, 0, stream>>>(head_idx, head_of, C);

    dim3 grid(NT, NJ / 128);
    k_mfma_max<<<grid, 256, 0, stream>>>((const unsigned short*)Knb,
                                         (const unsigned short*)Tnb, pv2, NT4);

    k_emitf<<<NJ / 4, 256, 0, stream>>>(pv2, wl, wl_count, cand, NT4);
    k_rescore2<<<256, 256, 0, stream>>>(wl, wl_count, K, rnK, Tn32, cand, P);
    k_logic<<<1, C, 0, stream>>>(head_idx, initial, cand, head_of, out, C);
}

// Round 5
// 81.198 us; speedup vs baseline: 1.5881x; 1.4785x over previous
//
#include <hip/hip_runtime.h>
#include <hip/hip_bf16.h>
#include <math.h>

// Problem: P=20000, d=128, C=512, h=4 (fixed dataset). d==128, h==4 assumed.
#define D_DIM 128
#define H_DIM 4

typedef __attribute__((ext_vector_type(4))) float f32x4;
typedef __attribute__((ext_vector_type(8))) __bf16 bf16x8v;

__device__ inline unsigned short f2bf(float f) {
    __hip_bfloat16 b = __float2bfloat16(f);
    return *reinterpret_cast<unsigned short*>(&b);
}

// ---- build normalized K rows in bf16 [Ppad][128] + 1/norm + init head_of/out ----
__global__ __launch_bounds__(256) void k_knb(
    const float* __restrict__ K, unsigned int* __restrict__ Knb,
    float* __restrict__ rnK, const float* __restrict__ initial,
    float* __restrict__ out, int* __restrict__ head_of, int P, int Ppad)
{
    int row = blockIdx.x * 4 + (threadIdx.x >> 6);
    int lane = threadIdx.x & 63;
    if (row >= Ppad) return;
    if (row >= P) { Knb[(size_t)row * 64 + lane] = 0u; return; }
    float2 v = ((const float2*)(K + (size_t)row * D_DIM))[lane];
    float ss = v.x * v.x + v.y * v.y;
    #pragma unroll
    for (int off = 1; off < 64; off <<= 1) ss += __shfl_xor(ss, off);
    float rn = 1.0f / fmaxf(sqrtf(ss), 1e-12f);
    unsigned int pk = (unsigned)f2bf(v.x * rn) | ((unsigned)f2bf(v.y * rn) << 16);
    Knb[(size_t)row * 64 + lane] = pk;
    if (lane == 0) {
        rnK[row] = rn;
        out[row] = initial[row];
        head_of[row] = 0x7FFFFFFF;
    }
}

// ---- normalized Theta rows (bf16 + fp32) and head_of scatter (after k_knb) ----
__global__ __launch_bounds__(256) void k_tn(
    const float* __restrict__ Theta, unsigned int* __restrict__ Tnb,
    float* __restrict__ Tn32, const int* __restrict__ head_idx,
    int* __restrict__ head_of, int C, int NJ)
{
    int g = blockIdx.x * 256 + (int)threadIdx.x;
    if (g < C) atomicMin(&head_of[head_idx[g]], g);

    int j = blockIdx.x * 4 + (threadIdx.x >> 6);
    int lane = threadIdx.x & 63;
    if (j >= NJ) return;
    int c = j >> 2, s = j & 3;
    const float* base = Theta + (size_t)c * (D_DIM * H_DIM) + s;
    float t0 = base[(2 * lane) * H_DIM];
    float t1 = base[(2 * lane + 1) * H_DIM];
    float ss = t0 * t0 + t1 * t1;
    #pragma unroll
    for (int off = 1; off < 64; off <<= 1) ss += __shfl_xor(ss, off);
    float rn = 1.0f / fmaxf(sqrtf(ss), 1e-12f);
    float n0 = t0 * rn, n1 = t1 * rn;
    Tnb[(size_t)j * 64 + lane] = (unsigned)f2bf(n0) | ((unsigned)f2bf(n1) << 16);
    float2 w; w.x = n0; w.y = n1;
    ((float2*)(Tn32 + (size_t)j * D_DIM))[lane] = w;
}

// ---- bf16 MFMA GEMM, fused per-(j, 32p-chunk) max.  D[j][p]=Tn·Kn^T ----
__global__ __launch_bounds__(256) void k_mfma_max(
    const unsigned short* __restrict__ Knb, const unsigned short* __restrict__ Tnb,
    float* __restrict__ pv2, int NT4)
{
    __shared__ __align__(16) unsigned short As[128 * 128];  // Tn tile  32 KB
    __shared__ __align__(16) unsigned short Bs[128 * 128];  // Kn tile  32 KB

    int tid = threadIdx.x;
    int p0 = blockIdx.x * 128, j0 = blockIdx.y * 128;
    int lane = tid & 63;
    int wave = tid >> 6;

    // stage via global_load_lds: linear LDS dest, inverse-XOR-swizzled global src.
    {
        int rr = lane >> 4, cc = lane & 15;
        const unsigned short* gA = Tnb + (size_t)j0 * 128;
        const unsigned short* gB = Knb + (size_t)p0 * 128;
        #pragma unroll
        for (int i = 0; i < 8; i++) {
            int r0 = wave * 32 + i * 4;
            int r = r0 + rr;
            int sc = (cc ^ (r & 7)) << 3;
            __builtin_amdgcn_global_load_lds(
                (const __attribute__((address_space(1))) unsigned int*)(gA + (size_t)r * 128 + sc),
                (__attribute__((address_space(3))) unsigned int*)&As[r0 * 128], 16, 0, 0);
            __builtin_amdgcn_global_load_lds(
                (const __attribute__((address_space(1))) unsigned int*)(gB + (size_t)r * 128 + sc),
                (__attribute__((address_space(3))) unsigned int*)&Bs[r0 * 128], 16, 0, 0);
        }
    }
    __syncthreads();

    int wm = wave >> 1, wn = wave & 1;
    int lr = lane & 15, lg = lane >> 4;

    f32x4 acc[4][4];
    #pragma unroll
    for (int m = 0; m < 4; m++)
        #pragma unroll
        for (int n = 0; n < 4; n++) { f32x4 z = {0.f, 0.f, 0.f, 0.f}; acc[m][n] = z; }

    #pragma unroll
    for (int ks = 0; ks < 4; ks++) {
        int koff = (8 * lg + 32 * ks) ^ ((lr & 7) << 3);
        bf16x8v af[4], bv[4];
        #pragma unroll
        for (int m = 0; m < 4; m++) {
            int row = 64 * wm + 16 * m + lr;
            af[m] = *(const bf16x8v*)&As[row * 128 + koff];
        }
        #pragma unroll
        for (int n = 0; n < 4; n++) {
            int row = 64 * wn + 16 * n + lr;
            bv[n] = *(const bf16x8v*)&Bs[row * 128 + koff];
        }
        #pragma unroll
        for (int m = 0; m < 4; m++)
            #pragma unroll
            for (int n = 0; n < 4; n++)
                acc[m][n] = __builtin_amdgcn_mfma_f32_16x16x32_bf16(af[m], bv[n], acc[m][n], 0, 0, 0);
    }

    // epilogue: per-32p-chunk max.  C/D: col(p)=lane&15, row(j)=4*(lane>>4)+reg
    __syncthreads();
    float* red = (float*)As;   // [128 j][4 chunk]
    #pragma unroll
    for (int m = 0; m < 4; m++) {
        #pragma unroll
        for (int n2 = 0; n2 < 2; n2++) {
            f32x4 a0 = acc[m][2 * n2], a1 = acc[m][2 * n2 + 1];
            float t0 = fmaxf(a0[0], a1[0]);
            float t1 = fmaxf(a0[1], a1[1]);
            float t2 = fmaxf(a0[2], a1[2]);
            float t3 = fmaxf(a0[3], a1[3]);
            #pragma unroll
            for (int off = 1; off <= 8; off <<= 1) {
                t0 = fmaxf(t0, __shfl_xor(t0, off));
                t1 = fmaxf(t1, __shfl_xor(t1, off));
                t2 = fmaxf(t2, __shfl_xor(t2, off));
                t3 = fmaxf(t3, __shfl_xor(t3, off));
            }
            if (lr == 0) {
                int jb = 64 * wm + 16 * m + 4 * lg;
                int ch = 2 * wn + n2;
                red[(jb + 0) * 4 + ch] = t0;
                red[(jb + 1) * 4 + ch] = t1;
                red[(jb + 2) * 4 + ch] = t2;
                red[(jb + 3) * 4 + ch] = t3;
            }
        }
    }
    __syncthreads();
    #pragma unroll
    for (int e = tid; e < 512; e += 256) {
        int jl = e >> 2, ch = e & 3;
        pv2[(size_t)(j0 + jl) * NT4 + blockIdx.x * 4 + ch] = red[jl * 4 + ch];
    }
}

// ---- fused threshold + prune + exact fp32 rescore: one wave per j, no atomics ----
__global__ __launch_bounds__(256) void k_prune(
    const float* __restrict__ pv2, const float* __restrict__ K,
    const float* __restrict__ rnK, const float* __restrict__ Tn32,
    float* __restrict__ conf, int* __restrict__ best, int P, int NT4)
{
    int wave = threadIdx.x >> 6, lane = threadIdx.x & 63;
    int j = blockIdx.x * 4 + wave;
    const float* row = pv2 + (size_t)j * NT4;

    // single pass: load all chunk maxes (NT4=628 <= 640) and reduce
    float v[10];
    float m = -INFINITY;
    #pragma unroll
    for (int i = 0; i < 10; i++) {
        int t = lane + i * 64;
        v[i] = (t < NT4) ? row[t] : -INFINITY;
        m = fmaxf(m, v[i]);
    }
    #pragma unroll
    for (int off = 32; off; off >>= 1) m = fmaxf(m, __shfl_xor(m, off));
    float thr = m - 0.009f;   // 2*eps bf16 unit-vector dot bound

    float bv = -INFINITY; int bbp = 0x7FFFFFFF;
    int half = lane & 1;      // which 64-elem half of the d-dim
    int pl = lane >> 1;       // p within chunk (0..31)
    #pragma unroll
    for (int i = 0; i < 10; i++) {
        unsigned long long ball = __ballot(v[i] >= thr);   // wave-uniform
        while (ball) {
            int bit = __ffsll(ball) - 1;
            ball &= ball - 1;
            int t = i * 64 + bit;
            int p = t * 32 + pl;
            bool ok = (p < P);
            int pc = ok ? p : 0;
            const float4* kp = (const float4*)(K + (size_t)pc * D_DIM + half * 64);
            const float4* tp = (const float4*)(Tn32 + (size_t)j * D_DIM + half * 64);
            float sx = 0.f, sy = 0.f, sz = 0.f, sw = 0.f;
            #pragma unroll
            for (int k4 = 0; k4 < 16; k4++) {
                float4 a = kp[k4], b = tp[k4];
                sx = fmaf(a.x, b.x, sx); sy = fmaf(a.y, b.y, sy);
                sz = fmaf(a.z, b.z, sz); sw = fmaf(a.w, b.w, sw);
            }
            float dot = (sx + sy) + (sz + sw);
            dot += __shfl_xor(dot, 1);      // combine d-halves
            float vv = ok ? dot * rnK[pc] : -INFINITY;
            int bp = p;
            #pragma unroll
            for (int off = 2; off < 64; off <<= 1) {
                float ov = __shfl_xor(vv, off);
                int op = __shfl_xor(bp, off);
                if (ov > vv || (ov == vv && op < bp)) { vv = ov; bp = op; }
            }
            if (vv > bv || (vv == bv && bp < bbp)) { bv = vv; bbp = bp; }
        }
    }
    if (lane == 0) { conf[j] = bv; best[j] = bbp; }
}

// ---- 6-iteration soft-logic loop, single block ----
__global__ __launch_bounds__(1024) void k_logic(
    const int* __restrict__ head_idx, const float* __restrict__ initial_val,
    const float* __restrict__ conf, const int* __restrict__ best,
    const int* __restrict__ head_of,
    float* __restrict__ out, int C)
{
    __shared__ float hval[1024];
    __shared__ float elds[1024];
    int c = threadIdx.x;   // blockDim.x == C
    int h = head_idx[c];
    int myslot = head_of[h];           // min clause index sharing this head
    hval[c] = initial_val[h];

    float cf[H_DIM], v0[H_DIM]; int bs[H_DIM];
    #pragma unroll
    for (int s = 0; s < H_DIM; s++) {
        int b = best[c * H_DIM + s];
        cf[s] = conf[c * H_DIM + s];
        v0[s] = initial_val[b];
        int ho = head_of[b];
        bs[s] = (ho < C) ? ho : -1;
    }
    __syncthreads();

    const float inv_tau = 20.0f;            // 1/TAU
    const float logn = logf(2.0f * H_DIM);  // log 8
    const float beta = 8.0f;

    for (int it = 0; it < 6; it++) {
        float x[2 * H_DIM];
        #pragma unroll
        for (int s = 0; s < H_DIM; s++) {
            x[s] = cf[s];
            x[H_DIM + s] = (bs[s] >= 0) ? hval[bs[s]] : v0[s];
        }
        float cur = hval[myslot];
        elds[c] = 0.f;
        __syncthreads();

        float m = x[0];
        #pragma unroll
        for (int i = 1; i < 2 * H_DIM; i++) m = fminf(m, x[i]);
        float ssum = 0.f;
        #pragma unroll
        for (int i = 0; i < 2 * H_DIM; i++) ssum += expf((m - x[i]) * inv_tau);
        float g = -inv_tau * ((-m * inv_tau + logf(ssum)) - logn);
        g = fminf(fmaxf(g, 0.f), 1.f);
        float w = expf(beta * g);
        atomicAdd(&elds[myslot], w);
        __syncthreads();

        float e = elds[myslot];
        float gh = logf(fmaxf(e, 1e-38f)) / beta;
        float nv = fmaxf(cur, gh);
        if (myslot == c) hval[c] = nv;
        __syncthreads();
    }

    if (myslot == c) out[h] = hval[c];
}

// ---------------- launch ----------------
extern "C" void kernel_launch(void* const* d_in, const int* in_sizes, int n_in,
                              void* d_out, int out_size, void* d_ws, size_t ws_size,
                              hipStream_t stream) {
    const float* K        = (const float*)d_in[0];
    const float* Theta    = (const float*)d_in[1];
    const int*   head_idx = (const int*)d_in[2];
    const float* initial  = (const float*)d_in[3];
    float* out = (float*)d_out;

    int P  = in_sizes[3];
    int C  = in_sizes[2];
    int NJ = C * H_DIM;                     // 2048
    int Ppad = ((P + 127) / 128) * 128;     // 20096
    int NT = Ppad / 128;                    // 157
    int NT4 = NT * 4;                       // 628 (32-p chunks)

    char* w = (char*)d_ws;
    size_t off = 0;
    auto alloc = [&](size_t bytes) { void* p = w + off; off += (bytes + 255) & ~(size_t)255; return p; };
    unsigned int* Knb  = (unsigned int*)alloc((size_t)Ppad * D_DIM * 2);
    unsigned int* Tnb  = (unsigned int*)alloc((size_t)NJ * D_DIM * 2);
    float* Tn32 = (float*)alloc((size_t)NJ * D_DIM * 4);
    float* rnK  = (float*)alloc((size_t)P * 4);
    float* pv2  = (float*)alloc((size_t)NJ * NT4 * 4);
    float* conf = (float*)alloc((size_t)NJ * 4);
    int*   best = (int*)alloc((size_t)NJ * 4);
    int* head_of = (int*)alloc((size_t)P * 4);
    (void)ws_size;

    k_knb<<<(Ppad + 3) / 4, 256, 0, stream>>>(K, Knb, rnK, initial, out, head_of, P, Ppad);
    k_tn<<<(NJ + 3) / 4, 256, 0, stream>>>(Theta, Tnb, Tn32, head_idx, head_of, C, NJ);

    dim3 grid(NT, NJ / 128);
    k_mfma_max<<<grid, 256, 0, stream>>>((const unsigned short*)Knb,
                                         (const unsigned short*)Tnb, pv2, NT4);

    k_prune<<<NJ / 4, 256, 0, stream>>>(pv2, K, rnK, Tn32, conf, best, P, NT4);
    k_logic<<<1, C, 0, stream>>>(head_idx, initial, conf, best, head_of, out, C);
}